// Round 6
// baseline (295.251 us; speedup 1.0000x reference)
//
#include <hip/hip_runtime.h>
#include <hip/hip_bf16.h>
#include <stdint.h>

// ---------- problem constants ----------
#define NB    16384     // batch
#define NCONT 13
#define NF    26
#define NV    100000
#define ND    16
#define NH    400       // H1 == H2
#define K1    448       // padded DNN_IN: [E(416) | cont(13) | pad(19)]
#define KP1   456       // LDS stride (shorts) for dnn tile
#define K2    416       // padded H1 (400 -> 416), layer-2 K
#define KP2   424       // LDS stride (shorts) for h1 tile
#define ROWS  64        // batch rows per block; grid = NB/ROWS = 256 = 1 block/CU
#define NW1   (NH * K1) // 179200 W1T elements
#define NTOT  (NH * K1 + NH * K2)   // 345600 total prep elements
#define PREPB ((NTOT + 255) / 256)  // 1350 prep elements per block
#define MAGIC 0x5EED0001u
// col-tiles: tile = wave + 4*j; tiles 0..24 cover cols 0..399 (no N padding).
// j==6 exists only for wave 0 (tile 24). Guard: (j<6 || wave==0), wave-uniform.

typedef __attribute__((ext_vector_type(8))) __bf16 bf16x8;
typedef __attribute__((ext_vector_type(8))) short short8;
typedef __attribute__((ext_vector_type(4))) float f32x4;

__device__ __forceinline__ short f2bf(float x) {
  union { float f; uint32_t u; } c; c.f = x;
  uint32_t r = (c.u + 0x7FFFu + ((c.u >> 16) & 1u)) >> 16;   // RNE
  return (short)(uint16_t)r;
}

// ---------- one GEMM layer: acc[4][7] += lds_tile @ WT^T (register-dbuf W) ----------
template <int K, int KP>
__device__ __forceinline__ void layer(const short* __restrict__ WT, const short* lds,
                                      int wave, bool w0, int lrow, int kq,
                                      f32x4 acc[4][7]) {
  const short* wb = WT + (size_t)(wave * 16 + lrow) * K + kq;   // tile j offset: j*64*K
  bf16x8 wf[2][7], af[2][4];
#pragma unroll
  for (int j = 0; j < 7; j++)
    if (j < 6 || w0) wf[0][j] = *(const bf16x8*)(wb + (size_t)j * 64 * K);
#pragma unroll
  for (int i = 0; i < 4; i++)
    af[0][i] = *(const bf16x8*)(lds + (i * 16 + lrow) * KP + kq);
#pragma unroll
  for (int ks = 0; ks < K / 32; ks++) {
    const int cur = ks & 1, nxt = cur ^ 1;
    if (ks + 1 < K / 32) {
#pragma unroll
      for (int j = 0; j < 7; j++)
        if (j < 6 || w0)
          wf[nxt][j] = *(const bf16x8*)(wb + (size_t)j * 64 * K + (ks + 1) * 32);
#pragma unroll
      for (int i = 0; i < 4; i++)
        af[nxt][i] = *(const bf16x8*)(lds + (i * 16 + lrow) * KP + (ks + 1) * 32 + kq);
    }
#pragma unroll
    for (int i = 0; i < 4; i++)
#pragma unroll
      for (int j = 0; j < 7; j++)
        if (j < 6 || w0)
          acc[i][j] = __builtin_amdgcn_mfma_f32_16x16x32_bf16(af[cur][i], wf[cur][j], acc[i][j], 0, 0, 0);
  }
}

// ---------- fused: [prep-slice -> flag] || gather+FM -> grid-barrier ->
//            layer1 -> LDS(aliased) -> layer2 -> out ----------
__global__ __launch_bounds__(256, 1)
void fused_k(const float* __restrict__ cont, const int* __restrict__ cat,
             const float* __restrict__ Wc, const float* __restrict__ bc,
             const float* __restrict__ emb1, const float* __restrict__ emb,
             const float* __restrict__ W1, const float* __restrict__ b1,
             const float* __restrict__ W2, const float* __restrict__ b2,
             const float* __restrict__ Wout, const float* __restrict__ bout,
             short* __restrict__ W1T, short* __restrict__ W2T,
             uint32_t* __restrict__ flags,
             float* __restrict__ out) {
  __shared__ short buf[ROWS * KP1];   // 58368 B; lA and lH alias this
  __shared__ float lP[4][ROWS];       // per-wave output partials
  __shared__ float lFM[ROWS];         // FM result per row
  short* lA = buf;
  short* lH = buf;
  const int tid = threadIdx.x;
  const int bm = blockIdx.x * ROWS;

  // ===== phase A0: this block's slice of weight prep =====
  {
    const int base = blockIdx.x * PREPB;
#pragma unroll
    for (int i = 0; i < (PREPB + 255) / 256; i++) {
      int o = i * 256 + tid;
      if (o < PREPB) {
        int g = base + o;
        if (g < NW1) {
          int n = g / K1, k = g - n * K1;
          float v = 0.f;
          if (k < 416)       v = W1[(size_t)(13 + k) * NH + n];   // E part
          else if (k < 429)  v = W1[(size_t)(k - 416) * NH + n];  // cont part
          W1T[g] = f2bf(v);
        } else if (g < NTOT) {
          int u = g - NW1;
          int n = u / K2, k = u - n * K2;
          float v = (k < NH) ? W2[(size_t)k * NH + n] : 0.f;
          W2T[u] = f2bf(v);
        }
      }
    }
  }
  __syncthreads();                // drains every thread's prep stores (vmcnt(0))
  if (tid == 0) {
    __threadfence();              // agent-release: XCD L2 writeback
    __hip_atomic_store(&flags[blockIdx.x], MAGIC,
                       __ATOMIC_RELEASE, __HIP_MEMORY_SCOPE_AGENT);
  }

  // ===== phase A1: gather + FM (4 lanes/row; prep stores drain underneath) =====
  {
    const int q  = tid & 3;
    const int rl = tid >> 2;
    const int b  = bm + rl;
    float se[16];
#pragma unroll
    for (int d = 0; d < 16; d++) se[d] = 0.f;
    float sumsq = 0.f, fm1 = 0.f;
    short* drow = lA + rl * KP1;

#pragma unroll
    for (int fi = 0; fi < 7; fi++) {
      const int f = q + 4 * fi;
      if (f < NF) {
        int idx = cat[(size_t)b * NF + f];
        const float4* ep = (const float4*)(emb + ((size_t)f * NV + idx) * ND);
        float4 e0 = ep[0], e1 = ep[1], e2 = ep[2], e3 = ep[3];
        fm1 += emb1[(size_t)f * NV + idx];
        se[0] += e0.x; se[1] += e0.y; se[2] += e0.z; se[3] += e0.w;
        se[4] += e1.x; se[5] += e1.y; se[6] += e1.z; se[7] += e1.w;
        se[8] += e2.x; se[9] += e2.y; se[10] += e2.z; se[11] += e2.w;
        se[12] += e3.x; se[13] += e3.y; se[14] += e3.z; se[15] += e3.w;
        sumsq += e0.x*e0.x + e0.y*e0.y + e0.z*e0.z + e0.w*e0.w
               + e1.x*e1.x + e1.y*e1.y + e1.z*e1.z + e1.w*e1.w
               + e2.x*e2.x + e2.y*e2.y + e2.z*e2.z + e2.w*e2.w
               + e3.x*e3.x + e3.y*e3.y + e3.z*e3.z + e3.w*e3.w;
        short8 p0, p1;
        p0[0]=f2bf(e0.x); p0[1]=f2bf(e0.y); p0[2]=f2bf(e0.z); p0[3]=f2bf(e0.w);
        p0[4]=f2bf(e1.x); p0[5]=f2bf(e1.y); p0[6]=f2bf(e1.z); p0[7]=f2bf(e1.w);
        p1[0]=f2bf(e2.x); p1[1]=f2bf(e2.y); p1[2]=f2bf(e2.z); p1[3]=f2bf(e2.w);
        p1[4]=f2bf(e3.x); p1[5]=f2bf(e3.y); p1[6]=f2bf(e3.z); p1[7]=f2bf(e3.w);
        *(short8*)(drow + f * 16)     = p0;
        *(short8*)(drow + f * 16 + 8) = p1;
      }
    }
    // reduce across the 4 lanes of this row (lane bits 0..1)
#pragma unroll
    for (int d = 0; d < 16; d++) {
      se[d] += __shfl_xor(se[d], 1, 64);
      se[d] += __shfl_xor(se[d], 2, 64);
    }
    sumsq += __shfl_xor(sumsq, 1, 64);
    sumsq += __shfl_xor(sumsq, 2, 64);
    fm1   += __shfl_xor(fm1, 1, 64);
    fm1   += __shfl_xor(fm1, 2, 64);

    if (q == 0) {
      float s2 = 0.f;
#pragma unroll
      for (int d = 0; d < 16; d++) s2 += se[d] * se[d];
      float fm2 = 0.5f * (s2 - sumsq);
      float fmc = bc[0];
      short tail[32];
#pragma unroll
      for (int i = 0; i < NCONT; i++) {
        float c = cont[(size_t)b * NCONT + i];
        fmc += c * Wc[i];
        tail[i] = f2bf(c);
      }
#pragma unroll
      for (int i = NCONT; i < 32; i++) tail[i] = 0;
#pragma unroll
      for (int v = 0; v < 4; v++) {
        short8 tv;
#pragma unroll
        for (int e = 0; e < 8; e++) tv[e] = tail[v * 8 + e];
        *(short8*)(drow + 416 + v * 8) = tv;
      }
      lFM[rl] = fm1 + fmc + fm2;
    }
  }

  // ===== grid barrier: wait until all 256 blocks published their W slices =====
  if (tid < 64) {
    for (;;) {
      uint32_t v0 = __hip_atomic_load(&flags[tid],       __ATOMIC_ACQUIRE, __HIP_MEMORY_SCOPE_AGENT);
      uint32_t v1 = __hip_atomic_load(&flags[tid + 64],  __ATOMIC_ACQUIRE, __HIP_MEMORY_SCOPE_AGENT);
      uint32_t v2 = __hip_atomic_load(&flags[tid + 128], __ATOMIC_ACQUIRE, __HIP_MEMORY_SCOPE_AGENT);
      uint32_t v3 = __hip_atomic_load(&flags[tid + 192], __ATOMIC_ACQUIRE, __HIP_MEMORY_SCOPE_AGENT);
      bool done = (v0 == MAGIC) && (v1 == MAGIC) && (v2 == MAGIC) && (v3 == MAGIC);
      if (__all(done)) break;
      __builtin_amdgcn_s_sleep(2);
    }
  }
  __syncthreads();   // whole block waits on wave 0; also orders lA tile for MFMA reads

  const int lane = tid & 63;
  const int wave = tid >> 6;
  const int lrow = lane & 15;
  const int quad = lane >> 4;
  const int kq   = quad * 8;
  const bool w0  = (wave == 0);
  f32x4 acc[4][7];

  // ----- layer 1: h1 = relu(dnn @ W1 + b1) -----
#pragma unroll
  for (int i = 0; i < 4; i++)
#pragma unroll
    for (int j = 0; j < 7; j++)
#pragma unroll
      for (int r = 0; r < 4; r++) acc[i][j][r] = 0.f;
  layer<K1, KP1>(W1T, lA, wave, w0, lrow, kq, acc);

  __syncthreads();   // all lA reads done before lH (aliased) writes

  // epilogue 1: bias+relu -> bf16 h1 tile
#pragma unroll
  for (int j = 0; j < 7; j++) {
    if (j < 6 || w0) {
      int col = (wave + 4 * j) * 16 + lrow;     // < 400 always
      float bias = b1[col];
#pragma unroll
      for (int i = 0; i < 4; i++)
#pragma unroll
        for (int r = 0; r < 4; r++) {
          int row = i * 16 + quad * 4 + r;
          lH[row * KP2 + col] = f2bf(fmaxf(acc[i][j][r] + bias, 0.f));
        }
    }
  }
  // zero pad cols 400..415 of lH (layer-2 K reads them)
  {
    int row = tid >> 2, g = tid & 3;
    *(uint2*)&lH[row * KP2 + 400 + g * 4] = make_uint2(0u, 0u);
  }
  __syncthreads();

  // ----- layer 2: h2 = relu(h1 @ W2 + b2), fused dot with Wout -----
#pragma unroll
  for (int i = 0; i < 4; i++)
#pragma unroll
    for (int j = 0; j < 7; j++)
#pragma unroll
      for (int r = 0; r < 4; r++) acc[i][j][r] = 0.f;
  layer<K2, KP2>(W2T, lH, wave, w0, lrow, kq, acc);

  // epilogue 2: relu + dot with Wout[1:], wave-reduce, LDS partials
  {
    float bw[7], wo[7];
#pragma unroll
    for (int j = 0; j < 7; j++) {
      bw[j] = 0.f; wo[j] = 0.f;
      if (j < 6 || w0) {
        int col = (wave + 4 * j) * 16 + lrow;
        bw[j] = b2[col];
        wo[j] = Wout[1 + col];
      }
    }
#pragma unroll
    for (int i = 0; i < 4; i++) {
#pragma unroll
      for (int r = 0; r < 4; r++) {
        float s = 0.f;
#pragma unroll
        for (int j = 0; j < 7; j++)
          if (j < 6 || w0) s += fmaxf(acc[i][j][r] + bw[j], 0.f) * wo[j];
        s += __shfl_xor(s, 1, 64);
        s += __shfl_xor(s, 2, 64);
        s += __shfl_xor(s, 4, 64);
        s += __shfl_xor(s, 8, 64);
        if (lrow == 0) lP[wave][i * 16 + quad * 4 + r] = s;
      }
    }
  }
  __syncthreads();

  // final: one coalesced store, no atomics
  if (tid < ROWS)
    out[bm + tid] = lFM[tid] * Wout[0] + bout[0]
                  + lP[0][tid] + lP[1][tid] + lP[2][tid] + lP[3][tid];
}

extern "C" void kernel_launch(void* const* d_in, const int* in_sizes, int n_in,
                              void* d_out, int out_size, void* d_ws, size_t ws_size,
                              hipStream_t stream) {
  const float* cont   = (const float*)d_in[0];
  const int*   cat    = (const int*)d_in[1];
  const float* W_cont = (const float*)d_in[2];
  const float* b_cont = (const float*)d_in[3];
  const float* emb1   = (const float*)d_in[4];
  const float* emb    = (const float*)d_in[5];
  const float* W1     = (const float*)d_in[6];
  const float* b1     = (const float*)d_in[7];
  const float* W2     = (const float*)d_in[8];
  const float* b2     = (const float*)d_in[9];
  const float* W_out  = (const float*)d_in[10];
  const float* b_out  = (const float*)d_in[11];
  float* out = (float*)d_out;

  char* ws = (char*)d_ws;
  short*    W1T   = (short*)ws;                              // 400*448*2 = 358400 B
  short*    W2T   = (short*)(ws + (size_t)NH * K1 * 2);      // 400*416*2 = 332800 B
  uint32_t* flags = (uint32_t*)(ws + (size_t)NH * (K1 + K2) * 2);  // 256 * 4 B
  (void)ws_size; (void)in_sizes; (void)n_in; (void)out_size;

  fused_k<<<dim3(NB / ROWS), dim3(256), 0, stream>>>(cont, cat, W_cont, b_cont,
                                                     emb1, emb, W1, b1, W2, b2,
                                                     W_out, b_out, W1T, W2T, flags, out);
}

// Round 7
// 270.756 us; speedup vs baseline: 1.0905x; 1.0905x over previous
//
#include <hip/hip_runtime.h>
#include <hip/hip_bf16.h>
#include <stdint.h>

// ---------- problem constants ----------
#define NB    16384     // batch
#define NCONT 13
#define NF    26
#define NV    100000
#define ND    16
#define NH    400       // H1 == H2
#define K1    448       // padded DNN_IN: [E(416) | cont(13) | pad(19)]
#define KP1   456       // LDS stride (shorts) for dnn tile
#define K2    416       // padded H1 (400 -> 416), layer-2 K
#define KP2   424       // LDS stride (shorts) for h1 tile
#define ROWS  64        // batch rows per block; grid = NB/ROWS = 256 = 1 block/CU
// prep thread ranges (coalesced-read layout):
#define P_W1   (429 * NH)            // 171600: read W1 row-major
#define P_W1Z  (P_W1 + 19 * NH)      // 179200: zero pad k=429..447
#define P_W2   (P_W1Z + NH * NH)     // 339200: read W2 row-major
#define P_TOT  (P_W2 + 16 * NH)      // 345600: zero pad k=400..415
// col-tiles: tile = wave + 4*j; tiles 0..24 cover cols 0..399 (no N padding).
// j==6 exists only for wave 0 (tile 24). Guard: (j<6 || wave==0), wave-uniform.

typedef __attribute__((ext_vector_type(8))) __bf16 bf16x8;
typedef __attribute__((ext_vector_type(8))) short short8;
typedef __attribute__((ext_vector_type(4))) float f32x4;

__device__ __forceinline__ short f2bf(float x) {
  union { float f; uint32_t u; } c; c.f = x;
  uint32_t r = (c.u + 0x7FFFu + ((c.u >> 16) & 1u)) >> 16;   // RNE
  return (short)(uint16_t)r;
}

// ---------- weight prep: coalesced READS, scattered writes ----------
// W1T[n*K1+k]: k<416 from W1 row 13+k; 416<=k<429 from W1 row k-416; k>=429 zero.
// W2T[n*K2+k]: k<400 from W2 row k; k>=400 zero.
__global__ __launch_bounds__(256)
void prep_k(const float* __restrict__ W1, const float* __restrict__ W2,
            short* __restrict__ W1T, short* __restrict__ W2T) {
  int t = blockIdx.x * 256 + threadIdx.x;
  if (t < P_W1) {                       // read W1[t] coalesced; r = row, n = col
    int r = t / NH, n = t - r * NH;
    int k = (r >= 13) ? (r - 13) : (416 + r);
    W1T[(size_t)n * K1 + k] = f2bf(W1[t]);
  } else if (t < P_W1Z) {               // zero pad of W1T
    int u = t - P_W1;
    int n = u / 19, k = 429 + (u - (u / 19) * 19);
    W1T[(size_t)n * K1 + k] = 0;
  } else if (t < P_W2) {                // read W2[u] coalesced; k = row, n = col
    int u = t - P_W1Z;
    int k = u / NH, n = u - k * NH;
    W2T[(size_t)n * K2 + k] = f2bf(W2[u]);
  } else {                              // zero pad of W2T
    int u = t - P_W2;
    int n = u / 16, k = 400 + (u & 15);
    W2T[(size_t)n * K2 + k] = 0;
  }
}

// ---------- one GEMM layer: acc[4][7] += lds_tile @ WT^T (register-dbuf W) ----------
template <int K, int KP>
__device__ __forceinline__ void layer(const short* __restrict__ WT, const short* lds,
                                      int wave, bool w0, int lrow, int kq,
                                      f32x4 acc[4][7]) {
  const short* wb = WT + (size_t)(wave * 16 + lrow) * K + kq;   // tile j offset: j*64*K
  bf16x8 wf[2][7], af[2][4];
#pragma unroll
  for (int j = 0; j < 7; j++)
    if (j < 6 || w0) wf[0][j] = *(const bf16x8*)(wb + (size_t)j * 64 * K);
#pragma unroll
  for (int i = 0; i < 4; i++)
    af[0][i] = *(const bf16x8*)(lds + (i * 16 + lrow) * KP + kq);
#pragma unroll
  for (int ks = 0; ks < K / 32; ks++) {
    const int cur = ks & 1, nxt = cur ^ 1;
    if (ks + 1 < K / 32) {
#pragma unroll
      for (int j = 0; j < 7; j++)
        if (j < 6 || w0)
          wf[nxt][j] = *(const bf16x8*)(wb + (size_t)j * 64 * K + (ks + 1) * 32);
#pragma unroll
      for (int i = 0; i < 4; i++)
        af[nxt][i] = *(const bf16x8*)(lds + (i * 16 + lrow) * KP + (ks + 1) * 32 + kq);
    }
#pragma unroll
    for (int i = 0; i < 4; i++)
#pragma unroll
      for (int j = 0; j < 7; j++)
        if (j < 6 || w0)
          acc[i][j] = __builtin_amdgcn_mfma_f32_16x16x32_bf16(af[cur][i], wf[cur][j], acc[i][j], 0, 0, 0);
  }
}

// ---------- fused: gather+FM -> LDS -> layer1 -> LDS(aliased) -> layer2 -> out ----------
__global__ __launch_bounds__(256, 1)
void fused_k(const float* __restrict__ cont, const int* __restrict__ cat,
             const float* __restrict__ Wc, const float* __restrict__ bc,
             const float* __restrict__ emb1, const float* __restrict__ emb,
             const short* __restrict__ W1T, const float* __restrict__ b1,
             const short* __restrict__ W2T, const float* __restrict__ b2,
             const float* __restrict__ Wout, const float* __restrict__ bout,
             float* __restrict__ out) {
  __shared__ short buf[ROWS * KP1];   // 58368 B; lA and lH alias this
  __shared__ float lP[4][ROWS];       // per-wave output partials
  __shared__ float lFM[ROWS];         // FM result per row
  short* lA = buf;
  short* lH = buf;
  const int tid = threadIdx.x;
  const int bm = blockIdx.x * ROWS;

  // ===== phase 1: gather + FM (4 lanes/row, unrolled => deep MLP) =====
  {
    const int q  = tid & 3;
    const int rl = tid >> 2;
    const int b  = bm + rl;
    float se[16];
#pragma unroll
    for (int d = 0; d < 16; d++) se[d] = 0.f;
    float sumsq = 0.f, fm1 = 0.f;
    short* drow = lA + rl * KP1;

#pragma unroll
    for (int fi = 0; fi < 7; fi++) {
      const int f = q + 4 * fi;
      if (f < NF) {
        int idx = cat[(size_t)b * NF + f];
        const float4* ep = (const float4*)(emb + ((size_t)f * NV + idx) * ND);
        float4 e0 = ep[0], e1 = ep[1], e2 = ep[2], e3 = ep[3];
        fm1 += emb1[(size_t)f * NV + idx];
        se[0] += e0.x; se[1] += e0.y; se[2] += e0.z; se[3] += e0.w;
        se[4] += e1.x; se[5] += e1.y; se[6] += e1.z; se[7] += e1.w;
        se[8] += e2.x; se[9] += e2.y; se[10] += e2.z; se[11] += e2.w;
        se[12] += e3.x; se[13] += e3.y; se[14] += e3.z; se[15] += e3.w;
        sumsq += e0.x*e0.x + e0.y*e0.y + e0.z*e0.z + e0.w*e0.w
               + e1.x*e1.x + e1.y*e1.y + e1.z*e1.z + e1.w*e1.w
               + e2.x*e2.x + e2.y*e2.y + e2.z*e2.z + e2.w*e2.w
               + e3.x*e3.x + e3.y*e3.y + e3.z*e3.z + e3.w*e3.w;
        short8 p0, p1;
        p0[0]=f2bf(e0.x); p0[1]=f2bf(e0.y); p0[2]=f2bf(e0.z); p0[3]=f2bf(e0.w);
        p0[4]=f2bf(e1.x); p0[5]=f2bf(e1.y); p0[6]=f2bf(e1.z); p0[7]=f2bf(e1.w);
        p1[0]=f2bf(e2.x); p1[1]=f2bf(e2.y); p1[2]=f2bf(e2.z); p1[3]=f2bf(e2.w);
        p1[4]=f2bf(e3.x); p1[5]=f2bf(e3.y); p1[6]=f2bf(e3.z); p1[7]=f2bf(e3.w);
        *(short8*)(drow + f * 16)     = p0;
        *(short8*)(drow + f * 16 + 8) = p1;
      }
    }
    // reduce across the 4 lanes of this row (lane bits 0..1)
#pragma unroll
    for (int d = 0; d < 16; d++) {
      se[d] += __shfl_xor(se[d], 1, 64);
      se[d] += __shfl_xor(se[d], 2, 64);
    }
    sumsq += __shfl_xor(sumsq, 1, 64);
    sumsq += __shfl_xor(sumsq, 2, 64);
    fm1   += __shfl_xor(fm1, 1, 64);
    fm1   += __shfl_xor(fm1, 2, 64);

    if (q == 0) {
      float s2 = 0.f;
#pragma unroll
      for (int d = 0; d < 16; d++) s2 += se[d] * se[d];
      float fm2 = 0.5f * (s2 - sumsq);
      float fmc = bc[0];
      short tail[32];
#pragma unroll
      for (int i = 0; i < NCONT; i++) {
        float c = cont[(size_t)b * NCONT + i];
        fmc += c * Wc[i];
        tail[i] = f2bf(c);
      }
#pragma unroll
      for (int i = NCONT; i < 32; i++) tail[i] = 0;
#pragma unroll
      for (int v = 0; v < 4; v++) {
        short8 tv;
#pragma unroll
        for (int e = 0; e < 8; e++) tv[e] = tail[v * 8 + e];
        *(short8*)(drow + 416 + v * 8) = tv;
      }
      lFM[rl] = fm1 + fmc + fm2;
    }
  }
  __syncthreads();

  const int lane = tid & 63;
  const int wave = tid >> 6;
  const int lrow = lane & 15;
  const int quad = lane >> 4;
  const int kq   = quad * 8;
  const bool w0  = (wave == 0);
  f32x4 acc[4][7];

  // ----- layer 1: h1 = relu(dnn @ W1 + b1) -----
#pragma unroll
  for (int i = 0; i < 4; i++)
#pragma unroll
    for (int j = 0; j < 7; j++)
#pragma unroll
      for (int r = 0; r < 4; r++) acc[i][j][r] = 0.f;
  layer<K1, KP1>(W1T, lA, wave, w0, lrow, kq, acc);

  __syncthreads();   // all lA reads done before lH (aliased) writes

  // epilogue 1: bias+relu -> bf16 h1 tile
#pragma unroll
  for (int j = 0; j < 7; j++) {
    if (j < 6 || w0) {
      int col = (wave + 4 * j) * 16 + lrow;     // < 400 always
      float bias = b1[col];
#pragma unroll
      for (int i = 0; i < 4; i++)
#pragma unroll
        for (int r = 0; r < 4; r++) {
          int row = i * 16 + quad * 4 + r;
          lH[row * KP2 + col] = f2bf(fmaxf(acc[i][j][r] + bias, 0.f));
        }
    }
  }
  // zero pad cols 400..415 of lH (layer-2 K reads them)
  {
    int row = tid >> 2, g = tid & 3;
    *(uint2*)&lH[row * KP2 + 400 + g * 4] = make_uint2(0u, 0u);
  }
  __syncthreads();

  // ----- layer 2: h2 = relu(h1 @ W2 + b2), fused dot with Wout -----
#pragma unroll
  for (int i = 0; i < 4; i++)
#pragma unroll
    for (int j = 0; j < 7; j++)
#pragma unroll
      for (int r = 0; r < 4; r++) acc[i][j][r] = 0.f;
  layer<K2, KP2>(W2T, lH, wave, w0, lrow, kq, acc);

  // epilogue 2: relu + dot with Wout[1:], wave-reduce, LDS partials
  {
    float bw[7], wo[7];
#pragma unroll
    for (int j = 0; j < 7; j++) {
      bw[j] = 0.f; wo[j] = 0.f;
      if (j < 6 || w0) {
        int col = (wave + 4 * j) * 16 + lrow;
        bw[j] = b2[col];
        wo[j] = Wout[1 + col];
      }
    }
#pragma unroll
    for (int i = 0; i < 4; i++) {
#pragma unroll
      for (int r = 0; r < 4; r++) {
        float s = 0.f;
#pragma unroll
        for (int j = 0; j < 7; j++)
          if (j < 6 || w0) s += fmaxf(acc[i][j][r] + bw[j], 0.f) * wo[j];
        s += __shfl_xor(s, 1, 64);
        s += __shfl_xor(s, 2, 64);
        s += __shfl_xor(s, 4, 64);
        s += __shfl_xor(s, 8, 64);
        if (lrow == 0) lP[wave][i * 16 + quad * 4 + r] = s;
      }
    }
  }
  __syncthreads();

  // final: one coalesced store, no atomics
  if (tid < ROWS)
    out[bm + tid] = lFM[tid] * Wout[0] + bout[0]
                  + lP[0][tid] + lP[1][tid] + lP[2][tid] + lP[3][tid];
}

extern "C" void kernel_launch(void* const* d_in, const int* in_sizes, int n_in,
                              void* d_out, int out_size, void* d_ws, size_t ws_size,
                              hipStream_t stream) {
  const float* cont   = (const float*)d_in[0];
  const int*   cat    = (const int*)d_in[1];
  const float* W_cont = (const float*)d_in[2];
  const float* b_cont = (const float*)d_in[3];
  const float* emb1   = (const float*)d_in[4];
  const float* emb    = (const float*)d_in[5];
  const float* W1     = (const float*)d_in[6];
  const float* b1     = (const float*)d_in[7];
  const float* W2     = (const float*)d_in[8];
  const float* b2     = (const float*)d_in[9];
  const float* W_out  = (const float*)d_in[10];
  const float* b_out  = (const float*)d_in[11];
  float* out = (float*)d_out;

  char* ws = (char*)d_ws;
  short* W1T = (short*)ws;                            // 400*448*2 = 358400 B
  short* W2T = (short*)(ws + (size_t)NH * K1 * 2);    // 400*416*2 = 332800 B
  (void)ws_size; (void)in_sizes; (void)n_in; (void)out_size;

  prep_k<<<dim3(P_TOT / 256), dim3(256), 0, stream>>>(W1, W2, W1T, W2T);
  fused_k<<<dim3(NB / ROWS), dim3(256), 0, stream>>>(cont, cat, W_cont, b_cont,
                                                     emb1, emb, W1T, b1, W2T, b2,
                                                     W_out, b_out, out);
}